// Round 9
// baseline (134.588 us; speedup 1.0000x reference)
//
#include <hip/hip_runtime.h>

// 8-level DWT + 8-level per-channel IDWT.
//  fwd03: levels 0-3 halo-fused per 256-wide lo3 tile. x is STAGED into LDS
//         with coalesced float4 loads and split into even/odd phase arrays;
//         all four levels then run the conflict-free split FIR.
//  mid_fused: fwd 4-7 + inv 7-4 per row (unchanged).
//  inverse levels 3..0: flat per-level kernels (unchanged).

static __constant__ float c_dec_lo[10] = {
    0.003335725285001549f, -0.012580751999015526f, -0.006241490213011705f,
    0.07757149384006515f, -0.03224486958502952f, -0.24229488706619015f,
    0.13842814590110342f, 0.7243085284385744f, 0.6038292697974729f,
    0.160102397974125f};
static __constant__ float c_dec_hi[10] = {
    -0.160102397974125f, 0.6038292697974729f, -0.7243085284385744f,
    0.13842814590110342f, 0.24229488706619015f, -0.03224486958502952f,
    -0.07757149384006515f, -0.006241490213011705f, 0.012580751999015526f,
    0.003335725285001549f};

__device__ inline float4 ldz4(const float* __restrict__ row, int j, int L) {
  if (j >= 0 && j + 3 < L) return *reinterpret_cast<const float4*>(row + j);
  float4 r;
  r.x = (j + 0 >= 0 && j + 0 < L) ? row[j + 0] : 0.f;
  r.y = (j + 1 >= 0 && j + 1 < L) ? row[j + 1] : 0.f;
  r.z = (j + 2 >= 0 && j + 2 < L) ? row[j + 2] : 0.f;
  r.w = (j + 3 >= 0 && j + 3 < L) ? row[j + 3] : 0.f;
  return r;
}

__device__ inline void load20(const float* src, int base, float* v) {
#pragma unroll
  for (int q = 0; q < 5; ++q) {
    const float4 t = *reinterpret_cast<const float4*>(src + base + 4 * q);
    v[4 * q + 0] = t.x; v[4 * q + 1] = t.y;
    v[4 * q + 2] = t.z; v[4 * q + 3] = t.w;
  }
}

__device__ inline void load12(const float* src, float* v) {
#pragma unroll
  for (int q = 0; q < 3; ++q) {
    const float4 t = *reinterpret_cast<const float4*>(src + 4 * q);
    v[4 * q + 0] = t.x; v[4 * q + 1] = t.y;
    v[4 * q + 2] = t.z; v[4 * q + 3] = t.w;
  }
}

__device__ inline void fir10x2(const float* v, float* lo, float* hv) {
#pragma unroll
  for (int i = 0; i < 4; ++i) {
    float a = 0.f, h = 0.f;
#pragma unroll
    for (int k = 0; k < 10; ++k) {
      const float xx = v[2 * i + 3 + k];
      a += xx * c_dec_lo[k];
      h += xx * c_dec_hi[k];
    }
    lo[i] = a; hv[i] = h;
  }
}

// Split-form FIR: lo[i] = sum_m o[i+1+m]*w[2m] + e[i+2+m]*w[2m+1]
__device__ inline void fir10x2_split(const float* e, const float* o,
                                     float* lo, float* hv) {
#pragma unroll
  for (int i = 0; i < 4; ++i) {
    float a = 0.f, h = 0.f;
#pragma unroll
    for (int m = 0; m < 5; ++m) {
      const float ov = o[i + 1 + m], ev = e[i + 2 + m];
      a += ov * c_dec_lo[2 * m] + ev * c_dec_lo[2 * m + 1];
      h += ov * c_dec_hi[2 * m] + ev * c_dec_hi[2 * m + 1];
    }
    lo[i] = a; hv[i] = h;
  }
}

__device__ inline void store_hi(float* hg, int A, int idx, const float* hv,
                                int es, int ee) {
  if (idx >= es && idx + 3 < ee) {
    *reinterpret_cast<float4*>(hg + A + idx) =
        make_float4(hv[0], hv[1], hv[2], hv[3]);
  } else {
#pragma unroll
    for (int i = 0; i < 4; ++i)
      if (idx + i >= es && idx + i < ee) hg[A + idx + i] = hv[i];
  }
}

__device__ inline void st4(float* dst, const float* a) {
  *reinterpret_cast<float4*>(dst) = make_float4(a[0], a[1], a[2], a[3]);
}

__device__ inline void store_pad_split(float* E, float* O, int idx,
                                       const float* lo, int vlo, int vhi) {
#pragma unroll
  for (int i = 0; i < 4; ++i) {
    const int s = idx + i;
    const float val = (s >= vlo && s < vhi) ? lo[i] : 0.f;
    if (s & 1) O[s >> 1] = val;
    else E[s >> 1] = val;
  }
}

// ---------------- fwd levels 0-3 fused (staged split-LDS), tile 256 ---------
// LDS layout (floats): Ex[0,2140) Ox[2140,4280) E0[4280,5348) O0[5348,6416)
// After level 0, Ex/Ox region is reused: E1@0(530) O1@532(530) E2@1064(262)
// O2@1328(262).  All b128 reads 16B-aligned; all LDS strides 8B or 16B/lane.
template <bool FAST>
__device__ inline void stage_x(const float* __restrict__ xr, float* Ex,
                               float* Ox, int xlo, int tid) {
  for (int u = tid; u < 1069; u += 256) {
    const float4 v = FAST
        ? *reinterpret_cast<const float4*>(xr + xlo + 4 * u)
        : ldz4(xr, xlo + 4 * u, 131072);
    *reinterpret_cast<float2*>(Ex + 2 * u) = make_float2(v.x, v.z);
    *reinterpret_cast<float2*>(Ox + 2 * u) = make_float2(v.y, v.w);
  }
}

template <bool FAST>
__device__ inline void fwd_levelN(const float* Ein, const float* Oin,
                                  float* Eout, float* Oout,
                                  float* __restrict__ hg, int A, int NOUT,
                                  int esHi, int eeFast, int vlo, int vhi,
                                  int tid) {
  const int ee = FAST ? eeFast : min(eeFast, vhi);
  for (int idx = 4 * tid; idx < NOUT; idx += 1024) {
    float e[12], o[12];
    load12(Ein + idx, e);
    load12(Oin + idx, o);
    float lo[4], hv[4];
    fir10x2_split(e, o, lo, hv);
    if (FAST) {
      const int j = idx >> 1;
      *reinterpret_cast<float2*>(Eout + j) = make_float2(lo[0], lo[2]);
      *reinterpret_cast<float2*>(Oout + j) = make_float2(lo[1], lo[3]);
      if (idx >= esHi && idx < ee) st4(hg + A + idx, hv);
    } else {
      store_pad_split(Eout, Oout, idx, lo, vlo, vhi);
      store_hi(hg, A, idx, hv, esHi, ee);
    }
  }
}

template <bool FAST>
__device__ inline void fwd_level3(const float* Ein, const float* Oin,
                                  float* __restrict__ l3,
                                  float* __restrict__ h3, int b3, int ne3,
                                  int tid) {
  for (int idx = 4 * tid; idx < 256; idx += 1024) {
    float e[12], o[12];
    load12(Ein + idx, e);
    load12(Oin + idx, o);
    float lo[4], hv[4];
    fir10x2_split(e, o, lo, hv);
    if (FAST) {
      st4(l3 + b3 + idx, lo);
      st4(h3 + b3 + idx, hv);
    } else {
      store_hi(l3, b3, idx, lo, 0, ne3);
      store_hi(h3, b3, idx, hv, 0, ne3);
    }
  }
}

__global__ __launch_bounds__(256) void fwd03(
    const float* __restrict__ x, float* __restrict__ hi0,
    float* __restrict__ hi1, float* __restrict__ hi2,
    float* __restrict__ hi3, float* __restrict__ lo3) {
  const int b = blockIdx.y;
  const int bx = blockIdx.x;
  const int b3 = bx * 256;
  __shared__ float W[6416];
  float* Ex = W;            // 2140 (stage; later E1/O1/E2/O2)
  float* Ox = W + 2140;     // 2140
  float* E0 = W + 4280;     // 1068
  float* O0 = W + 5348;     // 1068
  float* E1 = W;            // 530 (aliases dead Ex)
  float* O1 = W + 532;      // 530
  float* E2 = W + 1064;     // 262
  float* O2 = W + 1328;     // 262
  const int tid = threadIdx.x;
  const bool fast = (bx >= 1) && (bx <= 30);
  const float* xr = x + (size_t)b * 131072;
  float* h0 = hi0 + (size_t)b * 65540;
  float* h1 = hi1 + (size_t)b * 32772;
  float* h2 = hi2 + (size_t)b * 16388;
  float* h3 = hi3 + (size_t)b * 8196;
  float* l3 = lo3 + (size_t)b * 8196;
  const int A0 = 8 * b3 - 56, A1 = 4 * b3 - 24, A2 = 2 * b3 - 8;
  const int xlo = 2 * A0 - 8;

  if (fast) {
    stage_x<true>(xr, Ex, Ox, xlo, tid);
    __syncthreads();
    fwd_levelN<true>(Ex, Ox, E0, O0, h0, A0, 2132, 56, 2104, 0, 0, tid);
    __syncthreads();
    fwd_levelN<true>(E0, O0, E1, O1, h1, A1, 1060, 24, 1048, 0, 0, tid);
    __syncthreads();
    fwd_levelN<true>(E1, O1, E2, O2, h2, A2, 524, 8, 520, 0, 0, tid);
    __syncthreads();
    fwd_level3<true>(E2, O2, l3, h3, b3, 256, tid);
  } else {
    stage_x<false>(xr, Ex, Ox, xlo, tid);
    __syncthreads();
    fwd_levelN<false>(Ex, Ox, E0, O0, h0, A0, 2132, 56, 2104, -A0,
                      65537 - A0, tid);
    __syncthreads();
    fwd_levelN<false>(E0, O0, E1, O1, h1, A1, 1060, 24, 1048, -A1,
                      32769 - A1, tid);
    __syncthreads();
    fwd_levelN<false>(E1, O1, E2, O2, h2, A2, 524, 8, 520, -A2, 16385 - A2,
                      tid);
    __syncthreads();
    fwd_level3<false>(E2, O2, l3, h3, b3, min(256, 8193 - b3), tid);
  }
}

// ---------------- 8-output inverse accumulator (used by mid tail) -----------
__device__ inline void inv_accum(const float* p, const float* h,
                                 const float4* wpk, float* acc) {
#pragma unroll
  for (int i = 0; i < 8; ++i) acc[i] = 0.f;
#pragma unroll
  for (int m = 0; m < 16; ++m) {
    const float4 w = wpk[m];
#pragma unroll
    for (int e = 0; e < 4; ++e) {
      const float pe = p[e + 1 + m], he = h[e + 1 + m];
      acc[2 * e + 0] += pe * w.y + he * w.w;
      acc[2 * e + 1] += pe * w.x + he * w.z;
    }
  }
}

// ---------------- flat big inverse level: 16 outputs/thread -----------------
__global__ __launch_bounds__(256) void inv_big(
    const float* __restrict__ prev, const float* __restrict__ hicoef,
    const float* __restrict__ filt, int level, int L, int sIn, int Tout,
    int sOut, float* __restrict__ out) {
  const int c = blockIdx.y;
  __shared__ float4 wpack[16];
  const int tid = threadIdx.x;
  if (tid < 16) {
    const float* f = filt + ((size_t)c * 8 + level) * 64;
    wpack[tid] = make_float4(f[2 * tid], f[2 * tid + 1],
                             f[32 + 2 * tid], f[32 + 2 * tid + 1]);
  }
  __syncthreads();
  const int g = blockIdx.x * 256 + tid;
  const int t0 = 16 * g;
  if (t0 >= Tout) return;
  const int U = 8 * g - 8;
  const float* prow = prev + (size_t)c * sIn;
  const float* hrow = hicoef + (size_t)c * sIn;
  float p[24], h[24];
  const bool interior = (U >= 0) && (U + 23 < L) && (t0 + 15 < Tout);
  if (interior) {
#pragma unroll
    for (int q = 0; q < 6; ++q) {
      float4 a = *reinterpret_cast<const float4*>(prow + U + 4 * q);
      p[4 * q + 0] = a.x; p[4 * q + 1] = a.y; p[4 * q + 2] = a.z; p[4 * q + 3] = a.w;
      float4 bb = *reinterpret_cast<const float4*>(hrow + U + 4 * q);
      h[4 * q + 0] = bb.x; h[4 * q + 1] = bb.y; h[4 * q + 2] = bb.z; h[4 * q + 3] = bb.w;
    }
  } else {
#pragma unroll
    for (int q = 0; q < 24; ++q) {
      const int j = U + q;
      p[q] = (j >= 0 && j < L) ? prow[j] : 0.f;
      h[q] = (j >= 0 && j < L) ? hrow[j] : 0.f;
    }
  }
  float acc[16];
#pragma unroll
  for (int i = 0; i < 16; ++i) acc[i] = 0.f;
#pragma unroll
  for (int m = 0; m < 16; ++m) {
    const float4 w = wpack[m];
#pragma unroll
    for (int e = 0; e < 8; ++e) {
      const float pv = p[e + 1 + m], hv = h[e + 1 + m];
      acc[2 * e + 0] += pv * w.y + hv * w.w;
      acc[2 * e + 1] += pv * w.x + hv * w.z;
    }
  }
  float* orow = out + (size_t)c * sOut;
  if (interior) {
#pragma unroll
    for (int q = 0; q < 4; ++q)
      *reinterpret_cast<float4*>(orow + t0 + 4 * q) =
          make_float4(acc[4 * q], acc[4 * q + 1], acc[4 * q + 2], acc[4 * q + 3]);
  } else {
#pragma unroll
    for (int i = 0; i < 16; ++i)
      if (t0 + i < Tout) orow[t0 + i] = acc[i];
  }
}

// ---------------- middle: fwd 4-7 + inv 7-4, one block per row --------------
__device__ inline void fwd_tail_level(const float* __restrict__ in,
                                      float* __restrict__ outp, int L, int D,
                                      float* __restrict__ hirow, int tid) {
  for (int d0 = 4 * tid; d0 < D; d0 += 2048) {
    const int jb = 2 * d0 - 8;
    float v[20];
    const bool interior = (jb >= 0) && (jb + 19 < L) && (d0 + 3 < D);
    if (interior) {
      load20(in, jb, v);
    } else {
#pragma unroll
      for (int q = 0; q < 20; ++q) {
        const int j = jb + q;
        v[q] = (j >= 0 && j < L) ? in[j] : 0.f;
      }
    }
    float lo[4], hv[4];
    fir10x2(v, lo, hv);
    if (interior) {
      st4(outp + d0, lo);
      st4(hirow + d0, hv);
    } else {
#pragma unroll
      for (int i = 0; i < 4; ++i)
        if (d0 + i < D) { outp[d0 + i] = lo[i]; hirow[d0 + i] = hv[i]; }
    }
  }
}

__device__ inline void inv_tail_level(const float* __restrict__ pin,
                                      float* __restrict__ pout, int L,
                                      const float* __restrict__ hirow,
                                      const float* __restrict__ filt, int c,
                                      int level, int tid, float4* wpack) {
  __syncthreads();
  if (tid < 16) {
    const float* f = filt + ((size_t)c * 8 + level) * 64;
    wpack[tid] = make_float4(f[2 * tid], f[2 * tid + 1], f[32 + 2 * tid],
                             f[32 + 2 * tid + 1]);
  }
  __syncthreads();
  const int Tout = 2 * L - 1;
  for (int t0 = 8 * tid; t0 < Tout; t0 += 4096) {
    const int U = t0 / 2 - 8;
    float p[20], h[20];
    if (U >= 0 && U + 19 < L) {
      load20(pin, U, p);
      load20(hirow, U, h);
    } else {
#pragma unroll
      for (int q = 0; q < 20; ++q) {
        const int j = U + q;
        p[q] = (j >= 0 && j < L) ? pin[j] : 0.f;
        h[q] = (j >= 0 && j < L) ? hirow[j] : 0.f;
      }
    }
    float acc[8];
    inv_accum(p, h, wpack, acc);
    if (t0 + 7 < Tout) {
      st4(pout + t0, acc);
      st4(pout + t0 + 4, acc + 4);
    } else {
#pragma unroll
      for (int i = 0; i < 8; ++i)
        if (t0 + i < Tout) pout[t0 + i] = acc[i];
    }
  }
}

__global__ __launch_bounds__(512) void mid_fused(
    const float* __restrict__ lo3, const float* __restrict__ filt,
    float* __restrict__ prev3out) {
  const int b = blockIdx.x;
  __shared__ float A[8200];
  __shared__ float Bb[4104];
  __shared__ float H4[4100];
  __shared__ float H5[2052];
  __shared__ float H6[1028];
  __shared__ float H7[516];
  __shared__ float4 wpack[16];
  const int tid = threadIdx.x;
  const float* row = lo3 + (size_t)b * 8196;
  for (int j4 = tid; j4 < 2048; j4 += 512)
    *reinterpret_cast<float4*>(A + 4 * j4) =
        *reinterpret_cast<const float4*>(row + 4 * j4);
  if (tid == 0) A[8192] = row[8192];
  __syncthreads();
  fwd_tail_level(A, Bb, 8193, 4097, H4, tid);
  __syncthreads();
  fwd_tail_level(Bb, A, 4097, 2049, H5, tid);
  __syncthreads();
  fwd_tail_level(A, Bb, 2049, 1025, H6, tid);
  __syncthreads();
  fwd_tail_level(Bb, A, 1025, 513, H7, tid);
  inv_tail_level(A, Bb, 513, H7, filt, b, 7, tid, wpack);
  inv_tail_level(Bb, A, 1025, H6, filt, b, 6, tid, wpack);
  inv_tail_level(A, Bb, 2049, H5, filt, b, 5, tid, wpack);
  inv_tail_level(Bb, prev3out + (size_t)b * 8196, 4097, H4, filt, b, 4, tid,
                 wpack);
}

extern "C" void kernel_launch(void* const* d_in, const int* in_sizes, int n_in,
                              void* d_out, int out_size, void* d_ws,
                              size_t ws_size, hipStream_t stream) {
  const float* x = (const float*)d_in[0];
  const float* filt = (const float*)d_in[1];
  float* out = (float*)d_out;
  float* ws = (float*)d_ws;

  const int B = 128;
  float* lo3buf = ws;
  float* prev3buf = lo3buf + (size_t)B * 8196;
  float* hi0 = prev3buf + (size_t)B * 8196;
  float* hi1 = hi0 + (size_t)B * 65540;
  float* hi2 = hi1 + (size_t)B * 32772;
  float* hi3 = hi2 + (size_t)B * 16388;
  float* prev2buf = hi3 + (size_t)B * 8196;
  float* prev1buf = prev2buf + (size_t)B * 16388;
  float* prev0buf = prev1buf + (size_t)B * 32772;

  hipLaunchKernelGGL(fwd03, dim3(33, B), dim3(256), 0, stream, x, hi0, hi1,
                     hi2, hi3, lo3buf);
  hipLaunchKernelGGL(mid_fused, dim3(B), dim3(512), 0, stream, lo3buf, filt,
                     prev3buf);

  auto launch_inv = [&](const float* prev, const float* hv, int level, int L,
                        int sIn, int Tout, int sOut, float* dst) {
    const int tpr = (Tout + 15) / 16;
    dim3 grid((tpr + 255) / 256, B);
    hipLaunchKernelGGL(inv_big, grid, dim3(256), 0, stream, prev, hv, filt,
                       level, L, sIn, Tout, sOut, dst);
  };
  // inverse levels 3..0 (flat)
  launch_inv(prev3buf, hi3, 3, 8193, 8196, 16385, 16388, prev2buf);
  launch_inv(prev2buf, hi2, 2, 16385, 16388, 32769, 32772, prev1buf);
  launch_inv(prev1buf, hi1, 1, 32769, 32772, 65537, 65540, prev0buf);
  launch_inv(prev0buf, hi0, 0, 65537, 65540, 131072, 131072, out);
}

// Round 10
// 132.826 us; speedup vs baseline: 1.0133x; 1.0133x over previous
//
#include <hip/hip_runtime.h>

// 8-level DWT + 8-level per-channel IDWT.
//  fwd03: WAVE-LOCAL barrier-free pyramid. Each 64-lane wave owns a 128-wide
//         lo3 tile and runs levels 0-3 in its private LDS slice (split E/O).
//         No __syncthreads -> no vmcnt(0) drains of the hi global stores.
//  mid_fused: fwd 4-7 + inv 7-4 per row (unchanged).
//  inverse levels 3..0: flat per-level kernels (unchanged).

static __constant__ float c_dec_lo[10] = {
    0.003335725285001549f, -0.012580751999015526f, -0.006241490213011705f,
    0.07757149384006515f, -0.03224486958502952f, -0.24229488706619015f,
    0.13842814590110342f, 0.7243085284385744f, 0.6038292697974729f,
    0.160102397974125f};
static __constant__ float c_dec_hi[10] = {
    -0.160102397974125f, 0.6038292697974729f, -0.7243085284385744f,
    0.13842814590110342f, 0.24229488706619015f, -0.03224486958502952f,
    -0.07757149384006515f, -0.006241490213011705f, 0.012580751999015526f,
    0.003335725285001549f};

__device__ inline float4 ldz4(const float* __restrict__ row, int j, int L) {
  if (j >= 0 && j + 3 < L) return *reinterpret_cast<const float4*>(row + j);
  float4 r;
  r.x = (j + 0 >= 0 && j + 0 < L) ? row[j + 0] : 0.f;
  r.y = (j + 1 >= 0 && j + 1 < L) ? row[j + 1] : 0.f;
  r.z = (j + 2 >= 0 && j + 2 < L) ? row[j + 2] : 0.f;
  r.w = (j + 3 >= 0 && j + 3 < L) ? row[j + 3] : 0.f;
  return r;
}

__device__ inline void load20(const float* src, int base, float* v) {
#pragma unroll
  for (int q = 0; q < 5; ++q) {
    const float4 t = *reinterpret_cast<const float4*>(src + base + 4 * q);
    v[4 * q + 0] = t.x; v[4 * q + 1] = t.y;
    v[4 * q + 2] = t.z; v[4 * q + 3] = t.w;
  }
}

__device__ inline void load20z(const float* __restrict__ src, int base, int L,
                               float* v) {
#pragma unroll
  for (int q = 0; q < 5; ++q) {
    const float4 t = ldz4(src, base + 4 * q, L);
    v[4 * q + 0] = t.x; v[4 * q + 1] = t.y;
    v[4 * q + 2] = t.z; v[4 * q + 3] = t.w;
  }
}

__device__ inline void load12(const float* src, float* v) {
#pragma unroll
  for (int q = 0; q < 3; ++q) {
    const float4 t = *reinterpret_cast<const float4*>(src + 4 * q);
    v[4 * q + 0] = t.x; v[4 * q + 1] = t.y;
    v[4 * q + 2] = t.z; v[4 * q + 3] = t.w;
  }
}

__device__ inline void fir10x2(const float* v, float* lo, float* hv) {
#pragma unroll
  for (int i = 0; i < 4; ++i) {
    float a = 0.f, h = 0.f;
#pragma unroll
    for (int k = 0; k < 10; ++k) {
      const float xx = v[2 * i + 3 + k];
      a += xx * c_dec_lo[k];
      h += xx * c_dec_hi[k];
    }
    lo[i] = a; hv[i] = h;
  }
}

// Split-form FIR: lo[i] = sum_m o[i+1+m]*w[2m] + e[i+2+m]*w[2m+1]
__device__ inline void fir10x2_split(const float* e, const float* o,
                                     float* lo, float* hv) {
#pragma unroll
  for (int i = 0; i < 4; ++i) {
    float a = 0.f, h = 0.f;
#pragma unroll
    for (int m = 0; m < 5; ++m) {
      const float ov = o[i + 1 + m], ev = e[i + 2 + m];
      a += ov * c_dec_lo[2 * m] + ev * c_dec_lo[2 * m + 1];
      h += ov * c_dec_hi[2 * m] + ev * c_dec_hi[2 * m + 1];
    }
    lo[i] = a; hv[i] = h;
  }
}

__device__ inline void store_hi(float* hg, int A, int idx, const float* hv,
                                int es, int ee) {
  if (idx >= es && idx + 3 < ee) {
    *reinterpret_cast<float4*>(hg + A + idx) =
        make_float4(hv[0], hv[1], hv[2], hv[3]);
  } else {
#pragma unroll
    for (int i = 0; i < 4; ++i)
      if (idx + i >= es && idx + i < ee) hg[A + idx + i] = hv[i];
  }
}

__device__ inline void st4(float* dst, const float* a) {
  *reinterpret_cast<float4*>(dst) = make_float4(a[0], a[1], a[2], a[3]);
}

__device__ inline void store_pad_split(float* E, float* O, int idx,
                                       const float* lo, int vlo, int vhi) {
#pragma unroll
  for (int i = 0; i < 4; ++i) {
    const int s = idx + i;
    const float val = (s >= vlo && s < vhi) ? lo[i] : 0.f;
    if (s & 1) O[s >> 1] = val;
    else E[s >> 1] = val;
  }
}

// Wave-synchronous LDS fence: complete this wave's LDS ops, forbid compiler
// from moving LDS accesses across. No cross-wave cost (no s_barrier).
__device__ inline void wave_sync() {
  __builtin_amdgcn_wave_barrier();
  asm volatile("s_waitcnt lgkmcnt(0)" ::: "memory");
  __builtin_amdgcn_wave_barrier();
}

// ---------------- fwd levels 0-3: wave-local pyramid ----------------
// Per wave (tile T..T+128 of lo3): A2=2T-8 len 268, A1=4T-24 len 548,
// A0=8T-56 len 1108, x window base xoff=16T-120. Split E/O per level.
template <bool FAST>
__device__ inline void wl_level0(const float* __restrict__ xr, float* E0,
                                 float* O0, float* __restrict__ h0, int A0,
                                 int xoff, int vlo, int vhi, int eeh,
                                 int lane) {
#pragma unroll
  for (int i = 0; i < 5; ++i) {
    const int idx = 4 * lane + 256 * i;
    if (idx < 1108) {
      float v[20];
      if (FAST) load20(xr, 2 * idx + xoff, v);
      else load20z(xr, 2 * idx + xoff, 131072, v);
      float lo[4], hv[4];
      fir10x2(v, lo, hv);
      if (FAST) {
        const int j = idx >> 1;
        *reinterpret_cast<float2*>(E0 + j) = make_float2(lo[0], lo[2]);
        *reinterpret_cast<float2*>(O0 + j) = make_float2(lo[1], lo[3]);
        if (idx >= 56 && idx < 1080) st4(h0 + A0 + idx, hv);
      } else {
        store_pad_split(E0, O0, idx, lo, vlo, vhi);
        store_hi(h0, A0, idx, hv, 56, eeh);
      }
    }
  }
}

template <bool FAST>
__device__ inline void wl_levelN(const float* Ein, const float* Oin,
                                 float* Eout, float* Oout,
                                 float* __restrict__ hg, int A, int NOUT,
                                 int iters, int esHi, int eeHiF, int vlo,
                                 int vhi, int lane) {
  for (int i = 0; i < iters; ++i) {
    const int idx = 4 * lane + 256 * i;
    if (idx < NOUT) {
      float e[12], o[12];
      load12(Ein + idx, e);
      load12(Oin + idx, o);
      float lo[4], hv[4];
      fir10x2_split(e, o, lo, hv);
      if (FAST) {
        const int j = idx >> 1;
        *reinterpret_cast<float2*>(Eout + j) = make_float2(lo[0], lo[2]);
        *reinterpret_cast<float2*>(Oout + j) = make_float2(lo[1], lo[3]);
        if (idx >= esHi && idx < eeHiF) st4(hg + A + idx, hv);
      } else {
        store_pad_split(Eout, Oout, idx, lo, vlo, vhi);
        store_hi(hg, A, idx, hv, esHi, min(eeHiF, vhi));
      }
    }
  }
}

template <bool FAST>
__device__ inline void wl_level3(const float* Ein, const float* Oin,
                                 float* __restrict__ l3,
                                 float* __restrict__ h3, int T, int ne3,
                                 int lane) {
  const int idx = 4 * lane;
  if (idx >= 128) return;
  float e[12], o[12];
  load12(Ein + idx, e);
  load12(Oin + idx, o);
  float lo[4], hv[4];
  fir10x2_split(e, o, lo, hv);
  if (FAST) {
    st4(l3 + T + idx, lo);
    st4(h3 + T + idx, hv);
  } else {
    store_hi(l3, T, idx, lo, 0, ne3);
    store_hi(h3, T, idx, hv, 0, ne3);
  }
}

__global__ __launch_bounds__(256) void fwd03(
    const float* __restrict__ x, float* __restrict__ hi0,
    float* __restrict__ hi1, float* __restrict__ hi2,
    float* __restrict__ hi3, float* __restrict__ lo3) {
  const int b = blockIdx.y;
  const int widx = threadIdx.x >> 6;
  const int lane = threadIdx.x & 63;
  const int gw = blockIdx.x * 4 + widx;
  __shared__ float W[7744];  // 4 waves x 1936 floats
  float* E0 = W + widx * 1936;  // 556
  float* O0 = E0 + 556;         // 556
  float* E1 = O0 + 556;         // 276
  float* O1 = E1 + 276;         // 276
  float* E2 = O1 + 276;         // 136
  float* O2 = E2 + 136;         // 136
  if (gw > 64) return;  // whole-wave uniform; kernel has no __syncthreads
  const int T = gw * 128;
  const float* xr = x + (size_t)b * 131072;
  float* h0 = hi0 + (size_t)b * 65540;
  float* h1 = hi1 + (size_t)b * 32772;
  float* h2 = hi2 + (size_t)b * 16388;
  float* h3 = hi3 + (size_t)b * 8196;
  float* l3 = lo3 + (size_t)b * 8196;
  const int A0 = 8 * T - 56, A1 = 4 * T - 24, A2 = 2 * T - 8;
  const int xoff = 16 * T - 120;

  if (gw >= 1 && gw <= 62) {
    wl_level0<true>(xr, E0, O0, h0, A0, xoff, 0, 0, 0, lane);
    wave_sync();
    wl_levelN<true>(E0, O0, E1, O1, h1, A1, 548, 3, 24, 536, 0, 0, lane);
    wave_sync();
    wl_levelN<true>(E1, O1, E2, O2, h2, A2, 268, 2, 8, 264, 0, 0, lane);
    wave_sync();
    wl_level3<true>(E2, O2, l3, h3, T, 128, lane);
  } else {
    wl_level0<false>(xr, E0, O0, h0, A0, xoff, (A0 < 0) ? -A0 : 0,
                     min(1108, 65537 - A0), min(1080, 65537 - A0), lane);
    wave_sync();
    wl_levelN<false>(E0, O0, E1, O1, h1, A1, 548, 3, 24, 536,
                     (A1 < 0) ? -A1 : 0, min(548, 32769 - A1), lane);
    wave_sync();
    wl_levelN<false>(E1, O1, E2, O2, h2, A2, 268, 2, 8, 264,
                     (A2 < 0) ? -A2 : 0, min(268, 16385 - A2), lane);
    wave_sync();
    wl_level3<false>(E2, O2, l3, h3, T, min(128, 8193 - T), lane);
  }
}

// ---------------- 8-output inverse accumulator (used by mid tail) -----------
__device__ inline void inv_accum(const float* p, const float* h,
                                 const float4* wpk, float* acc) {
#pragma unroll
  for (int i = 0; i < 8; ++i) acc[i] = 0.f;
#pragma unroll
  for (int m = 0; m < 16; ++m) {
    const float4 w = wpk[m];
#pragma unroll
    for (int e = 0; e < 4; ++e) {
      const float pe = p[e + 1 + m], he = h[e + 1 + m];
      acc[2 * e + 0] += pe * w.y + he * w.w;
      acc[2 * e + 1] += pe * w.x + he * w.z;
    }
  }
}

// ---------------- flat big inverse level: 16 outputs/thread -----------------
__global__ __launch_bounds__(256) void inv_big(
    const float* __restrict__ prev, const float* __restrict__ hicoef,
    const float* __restrict__ filt, int level, int L, int sIn, int Tout,
    int sOut, float* __restrict__ out) {
  const int c = blockIdx.y;
  __shared__ float4 wpack[16];
  const int tid = threadIdx.x;
  if (tid < 16) {
    const float* f = filt + ((size_t)c * 8 + level) * 64;
    wpack[tid] = make_float4(f[2 * tid], f[2 * tid + 1],
                             f[32 + 2 * tid], f[32 + 2 * tid + 1]);
  }
  __syncthreads();
  const int g = blockIdx.x * 256 + tid;
  const int t0 = 16 * g;
  if (t0 >= Tout) return;
  const int U = 8 * g - 8;
  const float* prow = prev + (size_t)c * sIn;
  const float* hrow = hicoef + (size_t)c * sIn;
  float p[24], h[24];
  const bool interior = (U >= 0) && (U + 23 < L) && (t0 + 15 < Tout);
  if (interior) {
#pragma unroll
    for (int q = 0; q < 6; ++q) {
      float4 a = *reinterpret_cast<const float4*>(prow + U + 4 * q);
      p[4 * q + 0] = a.x; p[4 * q + 1] = a.y; p[4 * q + 2] = a.z; p[4 * q + 3] = a.w;
      float4 bb = *reinterpret_cast<const float4*>(hrow + U + 4 * q);
      h[4 * q + 0] = bb.x; h[4 * q + 1] = bb.y; h[4 * q + 2] = bb.z; h[4 * q + 3] = bb.w;
    }
  } else {
#pragma unroll
    for (int q = 0; q < 24; ++q) {
      const int j = U + q;
      p[q] = (j >= 0 && j < L) ? prow[j] : 0.f;
      h[q] = (j >= 0 && j < L) ? hrow[j] : 0.f;
    }
  }
  float acc[16];
#pragma unroll
  for (int i = 0; i < 16; ++i) acc[i] = 0.f;
#pragma unroll
  for (int m = 0; m < 16; ++m) {
    const float4 w = wpack[m];
#pragma unroll
    for (int e = 0; e < 8; ++e) {
      const float pv = p[e + 1 + m], hv = h[e + 1 + m];
      acc[2 * e + 0] += pv * w.y + hv * w.w;
      acc[2 * e + 1] += pv * w.x + hv * w.z;
    }
  }
  float* orow = out + (size_t)c * sOut;
  if (interior) {
#pragma unroll
    for (int q = 0; q < 4; ++q)
      *reinterpret_cast<float4*>(orow + t0 + 4 * q) =
          make_float4(acc[4 * q], acc[4 * q + 1], acc[4 * q + 2], acc[4 * q + 3]);
  } else {
#pragma unroll
    for (int i = 0; i < 16; ++i)
      if (t0 + i < Tout) orow[t0 + i] = acc[i];
  }
}

// ---------------- middle: fwd 4-7 + inv 7-4, one block per row --------------
__device__ inline void fwd_tail_level(const float* __restrict__ in,
                                      float* __restrict__ outp, int L, int D,
                                      float* __restrict__ hirow, int tid) {
  for (int d0 = 4 * tid; d0 < D; d0 += 2048) {
    const int jb = 2 * d0 - 8;
    float v[20];
    const bool interior = (jb >= 0) && (jb + 19 < L) && (d0 + 3 < D);
    if (interior) {
      load20(in, jb, v);
    } else {
#pragma unroll
      for (int q = 0; q < 20; ++q) {
        const int j = jb + q;
        v[q] = (j >= 0 && j < L) ? in[j] : 0.f;
      }
    }
    float lo[4], hv[4];
    fir10x2(v, lo, hv);
    if (interior) {
      st4(outp + d0, lo);
      st4(hirow + d0, hv);
    } else {
#pragma unroll
      for (int i = 0; i < 4; ++i)
        if (d0 + i < D) { outp[d0 + i] = lo[i]; hirow[d0 + i] = hv[i]; }
    }
  }
}

__device__ inline void inv_tail_level(const float* __restrict__ pin,
                                      float* __restrict__ pout, int L,
                                      const float* __restrict__ hirow,
                                      const float* __restrict__ filt, int c,
                                      int level, int tid, float4* wpack) {
  __syncthreads();
  if (tid < 16) {
    const float* f = filt + ((size_t)c * 8 + level) * 64;
    wpack[tid] = make_float4(f[2 * tid], f[2 * tid + 1], f[32 + 2 * tid],
                             f[32 + 2 * tid + 1]);
  }
  __syncthreads();
  const int Tout = 2 * L - 1;
  for (int t0 = 8 * tid; t0 < Tout; t0 += 4096) {
    const int U = t0 / 2 - 8;
    float p[20], h[20];
    if (U >= 0 && U + 19 < L) {
      load20(pin, U, p);
      load20(hirow, U, h);
    } else {
#pragma unroll
      for (int q = 0; q < 20; ++q) {
        const int j = U + q;
        p[q] = (j >= 0 && j < L) ? pin[j] : 0.f;
        h[q] = (j >= 0 && j < L) ? hirow[j] : 0.f;
      }
    }
    float acc[8];
    inv_accum(p, h, wpack, acc);
    if (t0 + 7 < Tout) {
      st4(pout + t0, acc);
      st4(pout + t0 + 4, acc + 4);
    } else {
#pragma unroll
      for (int i = 0; i < 8; ++i)
        if (t0 + i < Tout) pout[t0 + i] = acc[i];
    }
  }
}

__global__ __launch_bounds__(512) void mid_fused(
    const float* __restrict__ lo3, const float* __restrict__ filt,
    float* __restrict__ prev3out) {
  const int b = blockIdx.x;
  __shared__ float A[8200];
  __shared__ float Bb[4104];
  __shared__ float H4[4100];
  __shared__ float H5[2052];
  __shared__ float H6[1028];
  __shared__ float H7[516];
  __shared__ float4 wpack[16];
  const int tid = threadIdx.x;
  const float* row = lo3 + (size_t)b * 8196;
  for (int j4 = tid; j4 < 2048; j4 += 512)
    *reinterpret_cast<float4*>(A + 4 * j4) =
        *reinterpret_cast<const float4*>(row + 4 * j4);
  if (tid == 0) A[8192] = row[8192];
  __syncthreads();
  fwd_tail_level(A, Bb, 8193, 4097, H4, tid);
  __syncthreads();
  fwd_tail_level(Bb, A, 4097, 2049, H5, tid);
  __syncthreads();
  fwd_tail_level(A, Bb, 2049, 1025, H6, tid);
  __syncthreads();
  fwd_tail_level(Bb, A, 1025, 513, H7, tid);
  inv_tail_level(A, Bb, 513, H7, filt, b, 7, tid, wpack);
  inv_tail_level(Bb, A, 1025, H6, filt, b, 6, tid, wpack);
  inv_tail_level(A, Bb, 2049, H5, filt, b, 5, tid, wpack);
  inv_tail_level(Bb, prev3out + (size_t)b * 8196, 4097, H4, filt, b, 4, tid,
                 wpack);
}

extern "C" void kernel_launch(void* const* d_in, const int* in_sizes, int n_in,
                              void* d_out, int out_size, void* d_ws,
                              size_t ws_size, hipStream_t stream) {
  const float* x = (const float*)d_in[0];
  const float* filt = (const float*)d_in[1];
  float* out = (float*)d_out;
  float* ws = (float*)d_ws;

  const int B = 128;
  float* lo3buf = ws;
  float* prev3buf = lo3buf + (size_t)B * 8196;
  float* hi0 = prev3buf + (size_t)B * 8196;
  float* hi1 = hi0 + (size_t)B * 65540;
  float* hi2 = hi1 + (size_t)B * 32772;
  float* hi3 = hi2 + (size_t)B * 16388;
  float* prev2buf = hi3 + (size_t)B * 8196;
  float* prev1buf = prev2buf + (size_t)B * 16388;
  float* prev0buf = prev1buf + (size_t)B * 32772;

  hipLaunchKernelGGL(fwd03, dim3(17, B), dim3(256), 0, stream, x, hi0, hi1,
                     hi2, hi3, lo3buf);
  hipLaunchKernelGGL(mid_fused, dim3(B), dim3(512), 0, stream, lo3buf, filt,
                     prev3buf);

  auto launch_inv = [&](const float* prev, const float* hv, int level, int L,
                        int sIn, int Tout, int sOut, float* dst) {
    const int tpr = (Tout + 15) / 16;
    dim3 grid((tpr + 255) / 256, B);
    hipLaunchKernelGGL(inv_big, grid, dim3(256), 0, stream, prev, hv, filt,
                       level, L, sIn, Tout, sOut, dst);
  };
  // inverse levels 3..0 (flat)
  launch_inv(prev3buf, hi3, 3, 8193, 8196, 16385, 16388, prev2buf);
  launch_inv(prev2buf, hi2, 2, 16385, 16388, 32769, 32772, prev1buf);
  launch_inv(prev1buf, hi1, 1, 32769, 32772, 65537, 65540, prev0buf);
  launch_inv(prev0buf, hi0, 0, 65537, 65540, 131072, 131072, out);
}